// Round 1
// baseline (210.772 us; speedup 1.0000x reference)
//
#include <hip/hip_runtime.h>

// Problem: N=8192 tokens, K=4096 quant dim, D=1024 out dim.
// out[n, d] = W[d, argmax_k x[n, k]]   (first-occurrence tie-break)
//
// R1: column gather of row-major W amplified HBM fetch 16x -> transpose W
//     into d_ws (R2), FETCH 465->~145 MiB.
// R4: batch the 4 independent x-loads explicitly (ILP) + nontemporal on the
//     x stream / out stream (keep Wt resident in L2/IC).
// R5 (this round): wave-per-token argmax. Removes both __syncthreads, the
//     LDS round-trip, and the serial t==0 merge from every block's critical
//     path; 4 independent compare chains break the 16-deep dependent chain;
//     __shfl_xor butterfly leaves the winner in every lane (no broadcast).

constexpr int N = 8192;
constexpr int K = 4096;
constexpr int D = 1024;
constexpr int BLOCK = 256;            // 4 waves = 4 tokens per block
constexpr int TOK_PER_BLK = BLOCK / 64;

typedef float vf4 __attribute__((ext_vector_type(4))); // clang-native float4

// ---------------- Transpose W (D x K, row-major) -> Wt (K x D) ----------------
constexpr int TILE = 64;

__global__ __launch_bounds__(256) void transpose_W(
    const float* __restrict__ W, float* __restrict__ Wt)
{
    __shared__ float tile[TILE][TILE + 1];

    const int k0 = blockIdx.x * TILE;
    const int d0 = blockIdx.y * TILE;
    const int tx = threadIdx.x % 16;
    const int ty = threadIdx.x / 16;

    #pragma unroll
    for (int p = 0; p < 4; ++p) {
        const int r = p * 16 + ty; // d_local
        const vf4 v = __builtin_nontemporal_load(
            (const vf4*)(W + (size_t)(d0 + r) * K + k0 + tx * 4));
        tile[r][tx * 4 + 0] = v.x;
        tile[r][tx * 4 + 1] = v.y;
        tile[r][tx * 4 + 2] = v.z;
        tile[r][tx * 4 + 3] = v.w;
    }
    __syncthreads();
    #pragma unroll
    for (int p = 0; p < 4; ++p) {
        const int r = p * 16 + ty; // k_local
        vf4 o;
        o.x = tile[tx * 4 + 0][r];
        o.y = tile[tx * 4 + 1][r];
        o.z = tile[tx * 4 + 2][r];
        o.w = tile[tx * 4 + 3][r];
        // normal store: Wt is re-read by phase 2, keep it cacheable
        *(vf4*)(Wt + (size_t)(k0 + r) * D + d0 + tx * 4) = o;
    }
}

// ---------------- argmax + row gather from Wt: one wave per token ----------------
__global__ __launch_bounds__(BLOCK) void steq_argmax_gather(
    const float* __restrict__ x,
    const float* __restrict__ Wt,
    float* __restrict__ out)
{
    const int wave = threadIdx.x >> 6;
    const int lane = threadIdx.x & 63;
    const int n = blockIdx.x * TOK_PER_BLK + wave;

    const vf4* xv = (const vf4*)(x + (size_t)n * K); // 1024 vf4 per token

    // ---- Phase 1: load 16 float4 per lane (all independent, issued up front),
    // ---- nontemporal: x is streamed exactly once.
    vf4 v[16];
    #pragma unroll
    for (int i = 0; i < 16; ++i)
        v[i] = __builtin_nontemporal_load(&xv[i * 64 + lane]);

    // 4 independent compare chains, chain c covers i in [4c, 4c+4).
    // Per lane, every k in chain c is < every k in chain c+1, so an
    // in-order merge with strict '>' preserves first-occurrence.
    float bv[4];
    int   bi[4];
    #pragma unroll
    for (int c = 0; c < 4; ++c) { bv[c] = -__builtin_inff(); bi[c] = 0; }

    #pragma unroll
    for (int j = 0; j < 4; ++j) {
        #pragma unroll
        for (int c = 0; c < 4; ++c) {
            const int i = c * 4 + j;
            const vf4 w = v[i];
            const int base = (i * 64 + lane) * 4;
            if (w.x > bv[c]) { bv[c] = w.x; bi[c] = base + 0; }
            if (w.y > bv[c]) { bv[c] = w.y; bi[c] = base + 1; }
            if (w.z > bv[c]) { bv[c] = w.z; bi[c] = base + 2; }
            if (w.w > bv[c]) { bv[c] = w.w; bi[c] = base + 3; }
        }
    }
    // merge chains in ascending-k order (strict '>' keeps lower-k winner on tie)
    float best = bv[0];
    int  bidx = bi[0];
    #pragma unroll
    for (int c = 1; c < 4; ++c) {
        if (bv[c] > best) { best = bv[c]; bidx = bi[c]; }
    }

    // ---- Wave butterfly reduction: all 64 lanes end with the argmax.
    // first-occurrence tie-break: on equal value take smaller index.
    #pragma unroll
    for (int off = 32; off > 0; off >>= 1) {
        const float ov = __shfl_xor(best, off, 64);
        const int   oi = __shfl_xor(bidx, off, 64);
        if (ov > best || (ov == best && oi < bidx)) { best = ov; bidx = oi; }
    }
    const int k = bidx;

    // ---- Phase 2: out[n, :] = Wt[k, :] — contiguous 4 KiB per token.
    // Wt stays cacheable (rows reused ~2x across tokens, IC-resident);
    // out is streamed once -> nontemporal store.
    const vf4* wr = (const vf4*)(Wt + (size_t)k * D);   // 256 vf4
    vf4* orow = (vf4*)(out + (size_t)n * D);
    #pragma unroll
    for (int j = 0; j < 4; ++j) {
        const vf4 o = wr[j * 64 + lane];
        __builtin_nontemporal_store(o, &orow[j * 64 + lane]);
    }
}

extern "C" void kernel_launch(void* const* d_in, const int* in_sizes, int n_in,
                              void* d_out, int out_size, void* d_ws, size_t ws_size,
                              hipStream_t stream) {
    const float* x = (const float*)d_in[0];
    const float* W = (const float*)d_in[1];
    float* out = (float*)d_out;
    float* Wt  = (float*)d_ws; // K*D*4 = 16 MiB scratch

    dim3 tgrid(K / TILE, D / TILE); // (64, 16)
    transpose_W<<<tgrid, 256, 0, stream>>>(W, Wt);
    steq_argmax_gather<<<N / TOK_PER_BLK, BLOCK, 0, stream>>>(x, Wt, out);
}

// Round 2
// 210.120 us; speedup vs baseline: 1.0031x; 1.0031x over previous
//
#include <hip/hip_runtime.h>

// Problem: N=8192 tokens, K=4096 quant dim, D=1024 out dim.
// out[n, d] = W[d, argmax_k x[n, k]]   (first-occurrence tie-break)
//
// R1: column gather of row-major W amplified HBM fetch 16x -> transpose W
//     into d_ws (R2), FETCH 465->~145 MiB.
// R4: batch x-loads (ILP) + nontemporal on streamed data.
// R5: wave-per-token argmax (no LDS / no barriers) — neutral; reduction was
//     not on the critical path.
// R6 (this round): decouple phases.
//     Dispatch 1 = transpose blocks + argmax blocks in ONE grid (transpose
//       hidden under the 134 MB x stream; argmax is a ~pure-read BW kernel,
//       writes k[n] only).
//     Dispatch 2 = tiny pure row-gather out[n,:] = Wt[k[n],:] (~66 MB).
//     Removes the serial transpose dispatch and the per-wave latency tail
//     (reduce -> random Wt row -> store) that was diluting streaming BW.

constexpr int N = 8192;
constexpr int K = 4096;
constexpr int D = 1024;
constexpr int BLOCK = 256;            // 4 waves
constexpr int TOK_PER_BLK = BLOCK / 64;

typedef float vf4 __attribute__((ext_vector_type(4))); // clang-native float4

constexpr int TILE = 64;
constexpr int TRANS_BX = K / TILE;              // 64
constexpr int TRANS_BLOCKS = (K / TILE) * (D / TILE); // 1024
constexpr int ARGMAX_BLOCKS = N / TOK_PER_BLK;  // 2048

// ---------------- Dispatch 1: transpose W + argmax(x) fused in one grid ----------------
__global__ __launch_bounds__(BLOCK) void steq_phase1(
    const float* __restrict__ x,
    const float* __restrict__ W,
    float* __restrict__ Wt,
    int* __restrict__ kidx)
{
    __shared__ float tile[TILE][TILE + 1];

    if (blockIdx.x < TRANS_BLOCKS) {
        // ---- transpose tile: W (D x K) -> Wt (K x D) ----
        const int k0 = (blockIdx.x % TRANS_BX) * TILE;
        const int d0 = (blockIdx.x / TRANS_BX) * TILE;
        const int tx = threadIdx.x % 16;
        const int ty = threadIdx.x / 16;

        #pragma unroll
        for (int p = 0; p < 4; ++p) {
            const int r = p * 16 + ty; // d_local
            const vf4 v = __builtin_nontemporal_load(
                (const vf4*)(W + (size_t)(d0 + r) * K + k0 + tx * 4));
            tile[r][tx * 4 + 0] = v.x;
            tile[r][tx * 4 + 1] = v.y;
            tile[r][tx * 4 + 2] = v.z;
            tile[r][tx * 4 + 3] = v.w;
        }
        __syncthreads();
        #pragma unroll
        for (int p = 0; p < 4; ++p) {
            const int r = p * 16 + ty; // k_local
            vf4 o;
            o.x = tile[tx * 4 + 0][r];
            o.y = tile[tx * 4 + 1][r];
            o.z = tile[tx * 4 + 2][r];
            o.w = tile[tx * 4 + 3][r];
            // cacheable store: Wt re-read by dispatch 2 (IC-resident)
            *(vf4*)(Wt + (size_t)(k0 + r) * D + d0 + tx * 4) = o;
        }
        return;
    }

    // ---- argmax: one wave per token, pure x streaming ----
    const int wave = threadIdx.x >> 6;
    const int lane = threadIdx.x & 63;
    const int n = (blockIdx.x - TRANS_BLOCKS) * TOK_PER_BLK + wave;

    const vf4* xv = (const vf4*)(x + (size_t)n * K); // 1024 vf4 per token

    vf4 v[16];
    #pragma unroll
    for (int i = 0; i < 16; ++i)
        v[i] = __builtin_nontemporal_load(&xv[i * 64 + lane]);

    // 4 independent compare chains; chain c covers i in [4c, 4c+4).
    // Within a lane all k in chain c are < all k in chain c+1, so in-order
    // merge with strict '>' preserves first-occurrence semantics.
    float bv[4];
    int   bi[4];
    #pragma unroll
    for (int c = 0; c < 4; ++c) { bv[c] = -__builtin_inff(); bi[c] = 0; }

    #pragma unroll
    for (int j = 0; j < 4; ++j) {
        #pragma unroll
        for (int c = 0; c < 4; ++c) {
            const int i = c * 4 + j;
            const vf4 w = v[i];
            const int base = (i * 64 + lane) * 4;
            if (w.x > bv[c]) { bv[c] = w.x; bi[c] = base + 0; }
            if (w.y > bv[c]) { bv[c] = w.y; bi[c] = base + 1; }
            if (w.z > bv[c]) { bv[c] = w.z; bi[c] = base + 2; }
            if (w.w > bv[c]) { bv[c] = w.w; bi[c] = base + 3; }
        }
    }
    float best = bv[0];
    int  bidx = bi[0];
    #pragma unroll
    for (int c = 1; c < 4; ++c)
        if (bv[c] > best) { best = bv[c]; bidx = bi[c]; }

    // wave reduction; only lane 0's result is needed.
    #pragma unroll
    for (int off = 32; off > 0; off >>= 1) {
        const float ov = __shfl_down(best, off, 64);
        const int   oi = __shfl_down(bidx, off, 64);
        if (ov > best || (ov == best && oi < bidx)) { best = ov; bidx = oi; }
    }
    if (lane == 0) kidx[n] = bidx;
}

// ---------------- Dispatch 2: out[n, :] = Wt[k[n], :] ----------------
__global__ __launch_bounds__(BLOCK) void steq_gather(
    const float* __restrict__ Wt,
    const int* __restrict__ kidx,
    float* __restrict__ out)
{
    const int wave = threadIdx.x >> 6;
    const int lane = threadIdx.x & 63;
    const int n = blockIdx.x * TOK_PER_BLK + wave;

    const int k = kidx[n]; // wave-uniform, L2-broadcast

    const vf4* wr = (const vf4*)(Wt + (size_t)k * D);   // 256 vf4 (4 KiB)
    vf4* orow = (vf4*)(out + (size_t)n * D);
    vf4 o[4];
    #pragma unroll
    for (int j = 0; j < 4; ++j)
        o[j] = wr[j * 64 + lane];
    #pragma unroll
    for (int j = 0; j < 4; ++j)
        __builtin_nontemporal_store(o[j], &orow[j * 64 + lane]);
}

extern "C" void kernel_launch(void* const* d_in, const int* in_sizes, int n_in,
                              void* d_out, int out_size, void* d_ws, size_t ws_size,
                              hipStream_t stream) {
    const float* x = (const float*)d_in[0];
    const float* W = (const float*)d_in[1];
    float* out = (float*)d_out;
    float* Wt  = (float*)d_ws;                               // 16 MiB
    int*   kidx = (int*)((char*)d_ws + (size_t)K * D * 4);   // +32 KiB

    steq_phase1<<<TRANS_BLOCKS + ARGMAX_BLOCKS, BLOCK, 0, stream>>>(x, W, Wt, kidx);
    steq_gather<<<N / TOK_PER_BLK, BLOCK, 0, stream>>>(Wt, kidx, out);
}